// Round 4
// baseline (618.299 us; speedup 1.0000x reference)
//
#include <hip/hip_runtime.h>
#include <hip/hip_bf16.h>

#define B_   4
#define LQ_  1024
#define LK_  1024
#define LKL_ 512
#define DX_  1024
#define H_   16
#define DK_  64
#define HDK_ 1024
#define NEG_ -1e9f
#define EPS_ 1e-5f

typedef __bf16 bf16_t;
typedef __bf16 bf16x8 __attribute__((ext_vector_type(8)));
typedef __bf16 bf16x4 __attribute__((ext_vector_type(4)));
typedef float  f32x4  __attribute__((ext_vector_type(4)));

__device__ inline f32x4 mfma16(bf16x8 a, bf16x8 b, f32x4 c) {
    return __builtin_amdgcn_mfma_f32_16x16x32_bf16(a, b, c, 0, 0, 0);
}

__device__ __forceinline__ void gload16(const void* g, void* l) {
    __builtin_amdgcn_global_load_lds(
        (const __attribute__((address_space(1))) void*)g,
        (__attribute__((address_space(3))) void*)l, 16, 0, 0);
}

__device__ inline float waveMax(float v) {
#pragma unroll
    for (int o = 32; o > 0; o >>= 1) v = fmaxf(v, __shfl_xor(v, o, 64));
    return v;
}
__device__ inline float waveSum(float v) {
#pragma unroll
    for (int o = 32; o > 0; o >>= 1) v += __shfl_xor(v, o, 64);
    return v;
}

// XOR-swizzle for the attention score tile (16B slots XOR row bits).
template<int STRIDE>
__device__ inline int sidx(int row, int col) {
    return (row * STRIDE + col) ^ ((row & 15) << 3);
}

// ---------------------------------------------------------------------------
// Detect mask materialization: int32 (0), uint8 (1), float32 (2).
// ---------------------------------------------------------------------------
__global__ void detect_mask_kernel(const unsigned* __restrict__ m, unsigned* __restrict__ flag)
{
    __shared__ unsigned w[256];
    w[threadIdx.x] = m[threadIdx.x];
    __syncthreads();
    if (threadIdx.x == 0) {
        bool all01 = true, allf = true;
        for (int i = 0; i < 256; ++i) {
            unsigned v = w[i];
            all01 = all01 && (v <= 1u);
            allf  = allf  && (v == 0u || v == 0x3F800000u);
        }
        *flag = all01 ? 0u : (allf ? 2u : 1u);
    }
}

// ---------------------------------------------------------------------------
// Bit-pack both masks (1 = masked).
// ---------------------------------------------------------------------------
__global__ __launch_bounds__(256) void bitpack_mask_kernel(
    const void* __restrict__ mc, const void* __restrict__ ml,
    const unsigned* __restrict__ flagp,
    unsigned long long* __restrict__ bc, unsigned long long* __restrict__ bl)
{
    const unsigned flag = *flagp;
    const size_t NC = (size_t)B_ * LQ_ * LK_;
    const int lane = threadIdx.x & 63;
    const size_t g = (size_t)blockIdx.x * 256 + threadIdx.x;
    const bool inC = g < NC;
    const size_t idx = inC ? g : g - NC;
    const void* src = inC ? mc : ml;
    bool m;
    if (flag == 0u)      m = ((const int*)src)[idx] != 0;
    else if (flag == 2u) m = ((const float*)src)[idx] != 0.0f;
    else                 m = ((const unsigned char*)src)[idx] != 0;
    const unsigned long long bal = __ballot(m);
    if (lane == 0) {
        unsigned long long* dst = inC ? bc : bl;
        dst[idx >> 6] = bal;
    }
}

// ---------------------------------------------------------------------------
// f32 -> bf16 convert (8 elems/thread).
// ---------------------------------------------------------------------------
__global__ __launch_bounds__(256) void cvt_bf16_kernel(
    const float* __restrict__ src, bf16_t* __restrict__ dst, int n8)
{
    const int i = blockIdx.x * 256 + threadIdx.x;
    if (i >= n8) return;
    const float4 a = ((const float4*)src)[i * 2];
    const float4 b = ((const float4*)src)[i * 2 + 1];
    bf16x8 o;
    o[0] = (bf16_t)a.x; o[1] = (bf16_t)a.y; o[2] = (bf16_t)a.z; o[3] = (bf16_t)a.w;
    o[4] = (bf16_t)b.x; o[5] = (bf16_t)b.y; o[6] = (bf16_t)b.z; o[7] = (bf16_t)b.w;
    ((bf16x8*)dst)[i] = o;
}

// ---------------------------------------------------------------------------
// Weight transpose + convert: W (1024x1024 f32, KxN) -> Wt (NxK bf16).
// ---------------------------------------------------------------------------
__global__ __launch_bounds__(256) void wtrans_kernel(
    const float* __restrict__ W, bf16_t* __restrict__ Wt)
{
    __shared__ float T[64][65];
    const int k0 = blockIdx.y * 64, n0 = blockIdx.x * 64;
    const int t = threadIdx.x;
    const int lr = t >> 2, c0 = (t & 3) * 16;
#pragma unroll
    for (int j = 0; j < 4; ++j) {
        const float4 v = *(const float4*)&W[(size_t)(k0 + lr) * DX_ + n0 + c0 + j * 4];
        T[lr][c0 + j * 4 + 0] = v.x; T[lr][c0 + j * 4 + 1] = v.y;
        T[lr][c0 + j * 4 + 2] = v.z; T[lr][c0 + j * 4 + 3] = v.w;
    }
    __syncthreads();
    const int dr = t >> 2;
    bf16x8 o0, o1;
#pragma unroll
    for (int j = 0; j < 8; ++j) {
        o0[j] = (bf16_t)T[c0 + j][dr];
        o1[j] = (bf16_t)T[c0 + 8 + j][dr];
    }
    *(bf16x8*)&Wt[(size_t)(n0 + dr) * DX_ + k0 + c0]     = o0;
    *(bf16x8*)&Wt[(size_t)(n0 + dr) * DX_ + k0 + c0 + 8] = o1;
}

// ---------------------------------------------------------------------------
// m97-style GEMM: A(bf16 Mx1024) * Bt(bf16 1024x1024, = W^T) + bias.
// 128x128 tile, BK=64, 512 threads (8 waves 4x2), global_load_lds w16,
// XOR-swizzled LDS (slot ^= row&7), conflict-free ds_read_b128.
// MODE 0: bf16 head (B,H,L,DK).  MODE 1: bf16 V^T (B,H,DK,L).  MODE 2: f32+resid.
// ---------------------------------------------------------------------------
template<int MODE>
__global__ __launch_bounds__(512, 2) void gemm2_kernel(
    const bf16_t* __restrict__ A, const bf16_t* __restrict__ Bt,
    const float* __restrict__ bias,
    void* __restrict__ out, const float* __restrict__ resid, int lshift)
{
    __shared__ bf16_t As[128 * 64];
    __shared__ bf16_t Bs[128 * 64];
    char* const AsB = (char*)As;
    char* const BsB = (char*)Bs;
    const int tid = threadIdx.x, wave = tid >> 6, lane = tid & 63;
    const int m0 = blockIdx.y * 128, n0 = blockIdx.x * 128;
    const int wr4 = (wave >> 1) * 32, wc2 = (wave & 1) * 64;

    f32x4 acc[2][4] = {};

    const int srow = wave * 8 + (lane >> 3);   // + j*64
    const int sslot = lane & 7;

    for (int k0 = 0; k0 < 1024; k0 += 64) {
        __syncthreads();
#pragma unroll
        for (int j = 0; j < 2; ++j) {
            const int row = srow + j * 64;
            const int gs = sslot ^ (row & 7);
            gload16(&A[(size_t)(m0 + row) * 1024 + k0 + gs * 8],
                    AsB + j * 8192 + wave * 1024);
            gload16(&Bt[(size_t)(n0 + row) * 1024 + k0 + gs * 8],
                    BsB + j * 8192 + wave * 1024);
        }
        __syncthreads();
#pragma unroll
        for (int kk = 0; kk < 2; ++kk) {
            bf16x8 av[2], bv[4];
#pragma unroll
            for (int i = 0; i < 2; ++i) {
                const int r = wr4 + i * 16 + (lane & 15);
                av[i] = *(const bf16x8*)(AsB + r * 128 + (((kk * 4 + (lane >> 4)) ^ (r & 7)) * 16));
            }
#pragma unroll
            for (int n = 0; n < 4; ++n) {
                const int r = wc2 + n * 16 + (lane & 15);
                bv[n] = *(const bf16x8*)(BsB + r * 128 + (((kk * 4 + (lane >> 4)) ^ (r & 7)) * 16));
            }
#pragma unroll
            for (int i = 0; i < 2; ++i)
#pragma unroll
                for (int n = 0; n < 4; ++n)
                    acc[i][n] = mfma16(av[i], bv[n], acc[i][n]);
        }
    }

#pragma unroll
    for (int i = 0; i < 2; ++i) {
#pragma unroll
        for (int n = 0; n < 4; ++n) {
            const int col = n0 + wc2 + n * 16 + (lane & 15);
            const float bs = bias[col];
            const int row0 = m0 + wr4 + i * 16 + (lane >> 4) * 4;
            if (MODE == 1) {
                bf16x4 o;
#pragma unroll
                for (int r = 0; r < 4; ++r) o[r] = (bf16_t)(acc[i][n][r] + bs);
                const int b = row0 >> lshift, l = row0 & ((1 << lshift) - 1);
                const int h = col >> 6, d = col & 63;
                *(bf16x4*)&((bf16_t*)out)[(((size_t)(b * H_ + h) * DK_ + d) << lshift) + l] = o;
            } else if (MODE == 0) {
                const int b = row0 >> lshift, l = row0 & ((1 << lshift) - 1);
                const int h = col >> 6, d = col & 63;
#pragma unroll
                for (int r = 0; r < 4; ++r)
                    ((bf16_t*)out)[(((size_t)(b * H_ + h) << lshift) + l + r) * DK_ + d] =
                        (bf16_t)(acc[i][n][r] + bs);
            } else {
#pragma unroll
                for (int r = 0; r < 4; ++r) {
                    const size_t idx = (size_t)(row0 + r) * DX_ + col;
                    ((float*)out)[idx] = acc[i][n][r] + bs + resid[idx];
                }
            }
        }
    }
}

// ---------------------------------------------------------------------------
// Fused attention: 16 q-rows/block, branches SEQUENTIAL sharing one 32 KB
// score buffer -> 4 blocks/CU.
// ---------------------------------------------------------------------------
template<int LKX>
__device__ inline void scores16(bf16_t* __restrict__ Ssh, const bf16_t* __restrict__ Kb,
                                const bf16x8 qf[2], int wave, int lane)
{
    const int lr = lane & 15, lk8 = (lane >> 4) * 8;
    constexpr int KTS = LKX / 64;
#pragma unroll
    for (int kt = 0; kt < KTS; ++kt) {
        const int kbase = wave * (LKX / 4) + kt * 16;
        f32x4 acc = {};
#pragma unroll
        for (int ks = 0; ks < 2; ++ks) {
            const bf16x8 bb = *(const bf16x8*)&Kb[(size_t)(kbase + lr) * DK_ + ks * 32 + lk8];
            acc = mfma16(qf[ks], bb, acc);
        }
#pragma unroll
        for (int r = 0; r < 4; ++r) {
            const int row = (lane >> 4) * 4 + r;
            const int col = kbase + (lane & 15);
            Ssh[sidx<LKX>(row, col)] = (bf16_t)(acc[r] * 0.125f);
        }
    }
}

template<int LKX>
__device__ inline void softmax16(bf16_t* __restrict__ Ssh, const unsigned* __restrict__ bits,
                                 float* __restrict__ Sout, int b, int q0, int wave, int lane)
{
    constexpr int NP = LKX / 256;
#pragma unroll 1
    for (int i = 0; i < 4; ++i) {
        const int row = wave * 4 + i;
        const int rowg = q0 + row;
        const size_t rowbase = ((size_t)b * LQ_ + rowg) * LKX;
        float p[NP * 4];
        float m = -INFINITY;
#pragma unroll
        for (int ps = 0; ps < NP; ++ps) {
            const int col = ps * 256 + lane * 4;
            const bf16x4 sv = *(const bf16x4*)&Ssh[sidx<LKX>(row, col)];
            const unsigned word = bits[(rowbase + col) >> 5];
            const unsigned mb = word >> (col & 31);
#pragma unroll
            for (int j = 0; j < 4; ++j) {
                const float v = ((mb >> j) & 1u) ? NEG_ : (float)sv[j];
                p[ps * 4 + j] = v;
                m = fmaxf(m, v);
            }
        }
        m = waveMax(m);
        float s = 0.f;
#pragma unroll
        for (int j = 0; j < NP * 4; ++j) { p[j] = __expf(p[j] - m); s += p[j]; }
        s = waveSum(s);
        const float inv = 1.f / s;
#pragma unroll
        for (int ps = 0; ps < NP; ++ps) {
            const int col = ps * 256 + lane * 4;
            f32x4 o; bf16x4 pb;
#pragma unroll
            for (int j = 0; j < 4; ++j) {
                const float v = p[ps * 4 + j] * inv;
                o[j] = v; pb[j] = (bf16_t)v;
            }
            __builtin_nontemporal_store(o, (f32x4*)&Sout[(size_t)rowg * LKX + col]);
            *(bf16x4*)&Ssh[sidx<LKX>(row, col)] = pb;
        }
    }
}

template<int LKX>
__device__ inline void pv16(const bf16_t* __restrict__ Ssh, const bf16_t* __restrict__ Vtb,
                            f32x4& acc_o, int wave, int lane)
{
    const int lr = lane & 15, lk8 = (lane >> 4) * 8;
    const int d0 = wave * 16;
#pragma unroll
    for (int ks = 0; ks < LKX / 32; ++ks) {
        const bf16x8 bb = *(const bf16x8*)&Vtb[(size_t)(d0 + lr) * LKX + ks * 32 + lk8];
        const bf16x8 a  = *(const bf16x8*)&Ssh[sidx<LKX>(lr, ks * 32 + lk8)];
        acc_o = mfma16(a, bb, acc_o);
    }
}

__global__ __launch_bounds__(256, 4) void fused_attn_kernel(
    const bf16_t* __restrict__ Qh, const bf16_t* __restrict__ Kh,
    const bf16_t* __restrict__ Klh,
    const bf16_t* __restrict__ Vt, const bf16_t* __restrict__ Vlt,
    const unsigned* __restrict__ bitc, const unsigned* __restrict__ bitl,
    float* __restrict__ Sc, float* __restrict__ Sl, bf16_t* __restrict__ comb)
{
    __shared__ bf16_t Ssh[16 * 1024];   // 32 KB, reused by both branches
    const int sid = (blockIdx.x & 7) * 512 + (blockIdx.x >> 3);
    const int bh = sid >> 6, qt = sid & 63;
    const int b = bh >> 4, h = bh & 15;
    const int q0 = qt * 16;
    const int wave = threadIdx.x >> 6, lane = threadIdx.x & 63;
    const int lr = lane & 15, lk8 = (lane >> 4) * 8;

    const bf16_t* Qb = Qh + (size_t)bh * LQ_ * DK_;
    bf16x8 qf[2];
#pragma unroll
    for (int ks = 0; ks < 2; ++ks)
        qf[ks] = *(const bf16x8*)&Qb[(size_t)(q0 + lr) * DK_ + ks * 32 + lk8];

    f32x4 acc_o = {};

    // ---- branch c ----
    scores16<LK_>(Ssh, Kh + (size_t)bh * LK_ * DK_, qf, wave, lane);
    __syncthreads();
    softmax16<LK_>(Ssh, bitc, Sc + (size_t)bh * LQ_ * LK_, b, q0, wave, lane);
    __syncthreads();
    pv16<LK_>(Ssh, Vt + (size_t)bh * DK_ * LK_, acc_o, wave, lane);
    __syncthreads();
    // ---- branch l ----
    scores16<LKL_>(Ssh, Klh + (size_t)bh * LKL_ * DK_, qf, wave, lane);
    __syncthreads();
    softmax16<LKL_>(Ssh, bitl, Sl + (size_t)bh * LQ_ * LKL_, b, q0, wave, lane);
    __syncthreads();
    pv16<LKL_>(Ssh, Vlt + (size_t)bh * DK_ * LKL_, acc_o, wave, lane);

    const int d0 = wave * 16;
#pragma unroll
    for (int r = 0; r < 4; ++r) {
        const int row = q0 + (lane >> 4) * 4 + r;
        comb[((size_t)b * LQ_ + row) * HDK_ + h * DK_ + d0 + (lane & 15)] =
            (bf16_t)(0.5f * acc_o[r]);
    }
}

// ---------------------------------------------------------------------------
// LayerNorm over last dim (1024).
// ---------------------------------------------------------------------------
__global__ __launch_bounds__(256) void ln_kernel(
    const float* __restrict__ Y, const float* __restrict__ g,
    const float* __restrict__ be, float* __restrict__ out)
{
    __shared__ float red1[4], red2[4];
    const int tid = threadIdx.x, wave = tid >> 6, lane = tid & 63;
    const float* p = Y + (size_t)blockIdx.x * DX_;
    const float4 x = *(const float4*)&p[tid * 4];
    float s  = x.x + x.y + x.z + x.w;
    float ss = x.x * x.x + x.y * x.y + x.z * x.z + x.w * x.w;
    s = waveSum(s); ss = waveSum(ss);
    if (lane == 0) { red1[wave] = s; red2[wave] = ss; }
    __syncthreads();
    s  = red1[0] + red1[1] + red1[2] + red1[3];
    ss = red2[0] + red2[1] + red2[2] + red2[3];
    const float mean = s * (1.f / DX_);
    const float var  = ss * (1.f / DX_) - mean * mean;
    const float rstd = rsqrtf(var + EPS_);
    const float4 gg = *(const float4*)&g[tid * 4];
    const float4 bb = *(const float4*)&be[tid * 4];
    float4 o;
    o.x = (x.x - mean) * rstd * gg.x + bb.x;
    o.y = (x.y - mean) * rstd * gg.y + bb.y;
    o.z = (x.z - mean) * rstd * gg.z + bb.z;
    o.w = (x.w - mean) * rstd * gg.w + bb.w;
    *(float4*)&out[(size_t)blockIdx.x * DX_ + tid * 4] = o;
}

// ---------------------------------------------------------------------------
extern "C" void kernel_launch(void* const* d_in, const int* in_sizes, int n_in,
                              void* d_out, int out_size, void* d_ws, size_t ws_size,
                              hipStream_t stream)
{
    const float* q    = (const float*)d_in[0];
    const float* k    = (const float*)d_in[1];
    const float* v    = (const float*)d_in[2];
    const float* kl   = (const float*)d_in[3];
    const float* vl   = (const float*)d_in[4];
    const void*  mask  = d_in[5];
    const void*  maskl = d_in[6];
    const float* wq_w  = (const float*)d_in[7];
    const float* wq_b  = (const float*)d_in[8];
    const float* wk_w  = (const float*)d_in[9];
    const float* wk_b  = (const float*)d_in[10];
    const float* wv_w  = (const float*)d_in[11];
    const float* wv_b  = (const float*)d_in[12];
    const float* wkl_w = (const float*)d_in[13];
    const float* wkl_b = (const float*)d_in[14];
    const float* wvl_w = (const float*)d_in[15];
    const float* wvl_b = (const float*)d_in[16];
    const float* wo_w  = (const float*)d_in[17];
    const float* wo_b  = (const float*)d_in[18];
    const float* ln_g  = (const float*)d_in[19];
    const float* ln_b  = (const float*)d_in[20];

    char* ws = (char*)d_ws;
    const size_t MiB = 1u << 20;
    bf16_t* qb   = (bf16_t*)(ws);
    bf16_t* kb   = (bf16_t*)(ws +   8 * MiB);
    bf16_t* vb   = (bf16_t*)(ws +  16 * MiB);
    bf16_t* klb  = (bf16_t*)(ws +  24 * MiB);
    bf16_t* vlb  = (bf16_t*)(ws +  28 * MiB);
    bf16_t* qh   = (bf16_t*)(ws +  32 * MiB);
    bf16_t* kh   = (bf16_t*)(ws +  40 * MiB);
    bf16_t* klh  = (bf16_t*)(ws +  48 * MiB);
    bf16_t* vt   = (bf16_t*)(ws +  52 * MiB);
    bf16_t* vlt  = (bf16_t*)(ws +  60 * MiB);
    bf16_t* wqT  = (bf16_t*)(ws +  64 * MiB);
    bf16_t* wkT  = (bf16_t*)(ws +  66 * MiB);
    bf16_t* wvT  = (bf16_t*)(ws +  68 * MiB);
    bf16_t* wklT = (bf16_t*)(ws +  70 * MiB);
    bf16_t* wvlT = (bf16_t*)(ws +  72 * MiB);
    bf16_t* woT  = (bf16_t*)(ws +  74 * MiB);
    unsigned* flag = (unsigned*)(ws + 76 * MiB);
    unsigned long long* bitc = (unsigned long long*)(ws + 77 * MiB);
    unsigned long long* bitl = (unsigned long long*)(ws + 77 * MiB + 512 * 1024);
    bf16_t* comb = (bf16_t*)(ws + 78 * MiB);
    float*  ypre = (float*) (ws + 86 * MiB);

    float* y_out = (float*)d_out;
    float* Sc = y_out + (size_t)B_ * LQ_ * DX_;
    float* Sl = Sc + (size_t)B_ * H_ * LQ_ * LK_;

    detect_mask_kernel<<<dim3(1), dim3(256), 0, stream>>>((const unsigned*)mask, flag);
    bitpack_mask_kernel<<<dim3((B_*LQ_*(LK_+LKL_)) / 256), 256, 0, stream>>>(
        mask, maskl, flag, bitc, bitl);

    // Activations -> bf16
    cvt_bf16_kernel<<<2048, 256, 0, stream>>>(q,  qb,  524288);
    cvt_bf16_kernel<<<2048, 256, 0, stream>>>(k,  kb,  524288);
    cvt_bf16_kernel<<<2048, 256, 0, stream>>>(v,  vb,  524288);
    cvt_bf16_kernel<<<1024, 256, 0, stream>>>(kl, klb, 262144);
    cvt_bf16_kernel<<<1024, 256, 0, stream>>>(vl, vlb, 262144);

    // Weights -> bf16 transposed (NxK)
    wtrans_kernel<<<dim3(16, 16), 256, 0, stream>>>(wq_w,  wqT);
    wtrans_kernel<<<dim3(16, 16), 256, 0, stream>>>(wk_w,  wkT);
    wtrans_kernel<<<dim3(16, 16), 256, 0, stream>>>(wv_w,  wvT);
    wtrans_kernel<<<dim3(16, 16), 256, 0, stream>>>(wkl_w, wklT);
    wtrans_kernel<<<dim3(16, 16), 256, 0, stream>>>(wvl_w, wvlT);
    wtrans_kernel<<<dim3(16, 16), 256, 0, stream>>>(wo_w,  woT);

    // Projections
    gemm2_kernel<0><<<dim3(8, 32), 512, 0, stream>>>(qb,  wqT,  wq_b,  qh,  nullptr, 10);
    gemm2_kernel<0><<<dim3(8, 32), 512, 0, stream>>>(kb,  wkT,  wk_b,  kh,  nullptr, 10);
    gemm2_kernel<0><<<dim3(8, 16), 512, 0, stream>>>(klb, wklT, wkl_b, klh, nullptr,  9);
    gemm2_kernel<1><<<dim3(8, 32), 512, 0, stream>>>(vb,  wvT,  wv_b,  vt,  nullptr, 10);
    gemm2_kernel<1><<<dim3(8, 16), 512, 0, stream>>>(vlb, wvlT, wvl_b, vlt, nullptr,  9);

    // Fused scores+softmax+PV
    fused_attn_kernel<<<dim3(4096), 256, 0, stream>>>(qh, kh, klh, vt, vlt,
                                                      (const unsigned*)bitc, (const unsigned*)bitl,
                                                      Sc, Sl, comb);

    // Output projection + bias + residual(q)
    gemm2_kernel<2><<<dim3(8, 32), 512, 0, stream>>>(comb, woT, wo_b, ypre, q, 0);

    // LayerNorm
    ln_kernel<<<4096, 256, 0, stream>>>(ypre, ln_g, ln_b, y_out);
}

// Round 5
// 561.474 us; speedup vs baseline: 1.1012x; 1.1012x over previous
//
#include <hip/hip_runtime.h>
#include <hip/hip_bf16.h>

#define B_   4
#define LQ_  1024
#define LK_  1024
#define LKL_ 512
#define DX_  1024
#define H_   16
#define DK_  64
#define HDK_ 1024
#define NEG_ -1e9f
#define EPS_ 1e-5f

typedef __bf16 bf16_t;
typedef __bf16 bf16x8 __attribute__((ext_vector_type(8)));
typedef __bf16 bf16x4 __attribute__((ext_vector_type(4)));
typedef float  f32x4  __attribute__((ext_vector_type(4)));

__device__ inline f32x4 mfma16(bf16x8 a, bf16x8 b, f32x4 c) {
    return __builtin_amdgcn_mfma_f32_16x16x32_bf16(a, b, c, 0, 0, 0);
}

__device__ __forceinline__ void gload16(const void* g, void* l) {
    __builtin_amdgcn_global_load_lds(
        (const __attribute__((address_space(1))) void*)g,
        (__attribute__((address_space(3))) void*)l, 16, 0, 0);
}

__device__ inline float waveMax(float v) {
#pragma unroll
    for (int o = 32; o > 0; o >>= 1) v = fmaxf(v, __shfl_xor(v, o, 64));
    return v;
}
__device__ inline float waveSum(float v) {
#pragma unroll
    for (int o = 32; o > 0; o >>= 1) v += __shfl_xor(v, o, 64);
    return v;
}

// XOR-swizzle for the attention score tile (16B slots XOR row bits).
template<int STRIDE>
__device__ inline int sidx(int row, int col) {
    return (row * STRIDE + col) ^ ((row & 15) << 3);
}

// ---------------------------------------------------------------------------
// Detect mask materialization: int32 (0), uint8 (1), float32 (2).
// ---------------------------------------------------------------------------
__global__ void detect_mask_kernel(const unsigned* __restrict__ m, unsigned* __restrict__ flag)
{
    __shared__ unsigned w[256];
    w[threadIdx.x] = m[threadIdx.x];
    __syncthreads();
    if (threadIdx.x == 0) {
        bool all01 = true, allf = true;
        for (int i = 0; i < 256; ++i) {
            unsigned v = w[i];
            all01 = all01 && (v <= 1u);
            allf  = allf  && (v == 0u || v == 0x3F800000u);
        }
        *flag = all01 ? 0u : (allf ? 2u : 1u);
    }
}

// ---------------------------------------------------------------------------
// Bit-pack both masks (1 = masked).
// ---------------------------------------------------------------------------
__global__ __launch_bounds__(256) void bitpack_mask_kernel(
    const void* __restrict__ mc, const void* __restrict__ ml,
    const unsigned* __restrict__ flagp,
    unsigned long long* __restrict__ bc, unsigned long long* __restrict__ bl)
{
    const unsigned flag = *flagp;
    const size_t NC = (size_t)B_ * LQ_ * LK_;
    const int lane = threadIdx.x & 63;
    const size_t g = (size_t)blockIdx.x * 256 + threadIdx.x;
    const bool inC = g < NC;
    const size_t idx = inC ? g : g - NC;
    const void* src = inC ? mc : ml;
    bool m;
    if (flag == 0u)      m = ((const int*)src)[idx] != 0;
    else if (flag == 2u) m = ((const float*)src)[idx] != 0.0f;
    else                 m = ((const unsigned char*)src)[idx] != 0;
    const unsigned long long bal = __ballot(m);
    if (lane == 0) {
        unsigned long long* dst = inC ? bc : bl;
        dst[idx >> 6] = bal;
    }
}

// ---------------------------------------------------------------------------
// f32 -> bf16 convert (8 elems/thread).
// ---------------------------------------------------------------------------
__global__ __launch_bounds__(256) void cvt_bf16_kernel(
    const float* __restrict__ src, bf16_t* __restrict__ dst, int n8)
{
    const int i = blockIdx.x * 256 + threadIdx.x;
    if (i >= n8) return;
    const float4 a = ((const float4*)src)[i * 2];
    const float4 b = ((const float4*)src)[i * 2 + 1];
    bf16x8 o;
    o[0] = (bf16_t)a.x; o[1] = (bf16_t)a.y; o[2] = (bf16_t)a.z; o[3] = (bf16_t)a.w;
    o[4] = (bf16_t)b.x; o[5] = (bf16_t)b.y; o[6] = (bf16_t)b.z; o[7] = (bf16_t)b.w;
    ((bf16x8*)dst)[i] = o;
}

// ---------------------------------------------------------------------------
// Weight transpose + convert: W (1024x1024 f32, KxN) -> Wt (NxK bf16).
// ---------------------------------------------------------------------------
__global__ __launch_bounds__(256) void wtrans_kernel(
    const float* __restrict__ W, bf16_t* __restrict__ Wt)
{
    __shared__ float T[64][65];
    const int k0 = blockIdx.y * 64, n0 = blockIdx.x * 64;
    const int t = threadIdx.x;
    const int lr = t >> 2, c0 = (t & 3) * 16;
#pragma unroll
    for (int j = 0; j < 4; ++j) {
        const float4 v = *(const float4*)&W[(size_t)(k0 + lr) * DX_ + n0 + c0 + j * 4];
        T[lr][c0 + j * 4 + 0] = v.x; T[lr][c0 + j * 4 + 1] = v.y;
        T[lr][c0 + j * 4 + 2] = v.z; T[lr][c0 + j * 4 + 3] = v.w;
    }
    __syncthreads();
    const int dr = t >> 2;
    bf16x8 o0, o1;
#pragma unroll
    for (int j = 0; j < 8; ++j) {
        o0[j] = (bf16_t)T[c0 + j][dr];
        o1[j] = (bf16_t)T[c0 + 8 + j][dr];
    }
    *(bf16x8*)&Wt[(size_t)(n0 + dr) * DX_ + k0 + c0]     = o0;
    *(bf16x8*)&Wt[(size_t)(n0 + dr) * DX_ + k0 + c0 + 8] = o1;
}

// ---------------------------------------------------------------------------
// Transpose (bh, L, 64) -> (bh, 64, L) bf16 (coalesced both ways).
// ---------------------------------------------------------------------------
__global__ __launch_bounds__(256) void transpose_v_kernel(
    const bf16_t* __restrict__ V, bf16_t* __restrict__ Vt, int L)
{
    __shared__ bf16_t T[64][72];
    const int bh = blockIdx.y, l0 = blockIdx.x * 64;
    const bf16_t* Vb = V + (size_t)bh * L * 64;
    bf16_t* Vtb = Vt + (size_t)bh * 64 * L;
    const int t = threadIdx.x;
    {
        const int lr = t >> 2, dc = (t & 3) * 16;
        const bf16x8 a = *(const bf16x8*)&Vb[(size_t)(l0 + lr) * 64 + dc];
        const bf16x8 b = *(const bf16x8*)&Vb[(size_t)(l0 + lr) * 64 + dc + 8];
#pragma unroll
        for (int j = 0; j < 8; ++j) { T[lr][dc + j] = a[j]; T[lr][dc + 8 + j] = b[j]; }
    }
    __syncthreads();
    {
        const int dr = t >> 2, lc = (t & 3) * 16;
        bf16x8 o0, o1;
#pragma unroll
        for (int j = 0; j < 8; ++j) { o0[j] = T[lc + j][dr]; o1[j] = T[lc + 8 + j][dr]; }
        *(bf16x8*)&Vtb[(size_t)dr * L + l0 + lc]     = o0;
        *(bf16x8*)&Vtb[(size_t)dr * L + l0 + lc + 8] = o1;
    }
}

// ---------------------------------------------------------------------------
// m97-style GEMM: A(bf16 Mx1024) * Bt(bf16 1024x1024, = W^T) + bias.
// 128x128 tile, BK=64, 512 threads, global_load_lds w16, XOR-swizzled LDS.
// MODE 0: bf16 head (B,H,L,DK).  MODE 2: f32 + resid.
// ---------------------------------------------------------------------------
template<int MODE>
__global__ __launch_bounds__(512, 2) void gemm2_kernel(
    const bf16_t* __restrict__ A, const bf16_t* __restrict__ Bt,
    const float* __restrict__ bias,
    void* __restrict__ out, const float* __restrict__ resid, int lshift)
{
    __shared__ bf16_t As[128 * 64];
    __shared__ bf16_t Bs[128 * 64];
    char* const AsB = (char*)As;
    char* const BsB = (char*)Bs;
    const int tid = threadIdx.x, wave = tid >> 6, lane = tid & 63;
    const int m0 = blockIdx.y * 128, n0 = blockIdx.x * 128;
    const int wr4 = (wave >> 1) * 32, wc2 = (wave & 1) * 64;

    f32x4 acc[2][4] = {};

    const int srow = wave * 8 + (lane >> 3);
    const int sslot = lane & 7;

    for (int k0 = 0; k0 < 1024; k0 += 64) {
        __syncthreads();
#pragma unroll
        for (int j = 0; j < 2; ++j) {
            const int row = srow + j * 64;
            const int gs = sslot ^ (row & 7);
            gload16(&A[(size_t)(m0 + row) * 1024 + k0 + gs * 8],
                    AsB + j * 8192 + wave * 1024);
            gload16(&Bt[(size_t)(n0 + row) * 1024 + k0 + gs * 8],
                    BsB + j * 8192 + wave * 1024);
        }
        __syncthreads();
#pragma unroll
        for (int kk = 0; kk < 2; ++kk) {
            bf16x8 av[2], bv[4];
#pragma unroll
            for (int i = 0; i < 2; ++i) {
                const int r = wr4 + i * 16 + (lane & 15);
                av[i] = *(const bf16x8*)(AsB + r * 128 + (((kk * 4 + (lane >> 4)) ^ (r & 7)) * 16));
            }
#pragma unroll
            for (int n = 0; n < 4; ++n) {
                const int r = wc2 + n * 16 + (lane & 15);
                bv[n] = *(const bf16x8*)(BsB + r * 128 + (((kk * 4 + (lane >> 4)) ^ (r & 7)) * 16));
            }
#pragma unroll
            for (int i = 0; i < 2; ++i)
#pragma unroll
                for (int n = 0; n < 4; ++n)
                    acc[i][n] = mfma16(av[i], bv[n], acc[i][n]);
        }
    }

#pragma unroll
    for (int i = 0; i < 2; ++i) {
#pragma unroll
        for (int n = 0; n < 4; ++n) {
            const int col = n0 + wc2 + n * 16 + (lane & 15);
            const float bs = bias[col];
            const int row0 = m0 + wr4 + i * 16 + (lane >> 4) * 4;
            if (MODE == 0) {
                const int b = row0 >> lshift, l = row0 & ((1 << lshift) - 1);
                const int h = col >> 6, d = col & 63;
#pragma unroll
                for (int r = 0; r < 4; ++r)
                    ((bf16_t*)out)[(((size_t)(b * H_ + h) << lshift) + l + r) * DK_ + d] =
                        (bf16_t)(acc[i][n][r] + bs);
            } else {
#pragma unroll
                for (int r = 0; r < 4; ++r) {
                    const size_t idx = (size_t)(row0 + r) * DX_ + col;
                    ((float*)out)[idx] = acc[i][n][r] + bs + resid[idx];
                }
            }
        }
    }
}

// ---------------------------------------------------------------------------
// Fused attention, 16 q-rows/block, mask applied at score write-back,
// 3-pass in-LDS softmax (no register row buffer -> no spill),
// deferred 1/sum applied in the PV epilogue.
// ---------------------------------------------------------------------------
template<int LKX>
__device__ inline void scores16(bf16_t* __restrict__ Ssh, const bf16_t* __restrict__ Kb,
                                const bf16x8 qf[2], const unsigned* __restrict__ mbits,
                                int wave, int lane)
{
    const int lr = lane & 15, lk8 = (lane >> 4) * 8;
    constexpr int WORDS = LKX / 32;
    constexpr int KTS = LKX / 64;
#pragma unroll
    for (int kt = 0; kt < KTS; ++kt) {
        const int kbase = wave * (LKX / 4) + kt * 16;
        f32x4 acc = {};
#pragma unroll
        for (int ks = 0; ks < 2; ++ks) {
            const bf16x8 bb = *(const bf16x8*)&Kb[(size_t)(kbase + lr) * DK_ + ks * 32 + lk8];
            acc = mfma16(qf[ks], bb, acc);
        }
        const int wi = kbase >> 5;
        const int sh = (kbase & 16) + (lane & 15);
#pragma unroll
        for (int r = 0; r < 4; ++r) {
            const int row = (lane >> 4) * 4 + r;
            const bool msk = (mbits[row * WORDS + wi] >> sh) & 1u;
            const float val = msk ? NEG_ : acc[r] * 0.125f;
            Ssh[sidx<LKX>(row, kbase + (lane & 15))] = (bf16_t)val;
        }
    }
}

template<int LKX>
__device__ inline void softmax16(bf16_t* __restrict__ Ssh, float* __restrict__ Sout,
                                 float* __restrict__ invs, int q0, int wave, int lane)
{
    constexpr int NP = LKX / 256;
#pragma unroll 1
    for (int i = 0; i < 4; ++i) {
        const int row = wave * 4 + i;
        const int rowg = q0 + row;
        float m = -INFINITY;
#pragma unroll
        for (int ps = 0; ps < NP; ++ps) {
            const bf16x4 sv = *(const bf16x4*)&Ssh[sidx<LKX>(row, ps * 256 + lane * 4)];
#pragma unroll
            for (int j = 0; j < 4; ++j) m = fmaxf(m, (float)sv[j]);
        }
        m = waveMax(m);
        float s = 0.f;
#pragma unroll
        for (int ps = 0; ps < NP; ++ps) {
            const int ix = sidx<LKX>(row, ps * 256 + lane * 4);
            const bf16x4 sv = *(const bf16x4*)&Ssh[ix];
            bf16x4 e;
#pragma unroll
            for (int j = 0; j < 4; ++j) {
                const float v = __expf((float)sv[j] - m);
                s += v; e[j] = (bf16_t)v;
            }
            *(bf16x4*)&Ssh[ix] = e;
        }
        s = waveSum(s);
        const float inv = 1.f / s;
        if (lane == 0) invs[row] = inv;
#pragma unroll
        for (int ps = 0; ps < NP; ++ps) {
            const int col = ps * 256 + lane * 4;
            const bf16x4 e = *(const bf16x4*)&Ssh[sidx<LKX>(row, col)];
            f32x4 o;
#pragma unroll
            for (int j = 0; j < 4; ++j) o[j] = (float)e[j] * inv;
            __builtin_nontemporal_store(o, (f32x4*)&Sout[(size_t)rowg * LKX + col]);
        }
    }
}

template<int LKX>
__device__ inline void pv16(const bf16_t* __restrict__ Ssh, const bf16_t* __restrict__ Vtb,
                            f32x4& acc_o, int wave, int lane)
{
    const int lr = lane & 15, lk8 = (lane >> 4) * 8;
    const int d0 = wave * 16;
#pragma unroll
    for (int ks = 0; ks < LKX / 32; ++ks) {
        const bf16x8 bb = *(const bf16x8*)&Vtb[(size_t)(d0 + lr) * LKX + ks * 32 + lk8];
        const bf16x8 a  = *(const bf16x8*)&Ssh[sidx<LKX>(lr, ks * 32 + lk8)];
        acc_o = mfma16(a, bb, acc_o);
    }
}

__global__ __launch_bounds__(256, 3) void fused_attn_kernel(
    const bf16_t* __restrict__ Qh, const bf16_t* __restrict__ Kh,
    const bf16_t* __restrict__ Klh,
    const bf16_t* __restrict__ Vt, const bf16_t* __restrict__ Vlt,
    const unsigned* __restrict__ bitc, const unsigned* __restrict__ bitl,
    float* __restrict__ Sc, float* __restrict__ Sl, bf16_t* __restrict__ comb)
{
    __shared__ bf16_t Ssh[16 * 1024];        // 32 KB, reused by both branches
    __shared__ unsigned mwords[16 * 32 + 16 * 16];   // 3 KB: c bits then l bits
    __shared__ float invs_c[16], invs_l[16];
    unsigned* const mb_c = mwords;
    unsigned* const mb_l = mwords + 16 * 32;

    const int sid = (blockIdx.x & 7) * 512 + (blockIdx.x >> 3);
    const int bh = sid >> 6, qt = sid & 63;
    const int b = bh >> 4, h = bh & 15;
    const int q0 = qt * 16;
    const int wave = threadIdx.x >> 6, lane = threadIdx.x & 63;
    const int lr = lane & 15, lk8 = (lane >> 4) * 8;
    const int t = threadIdx.x;

    // stage mask bits: c = 16 rows x 32 words, l = 16 rows x 16 words
    for (int w = t; w < 512; w += 256)
        mb_c[w] = bitc[((size_t)(b * LQ_ + q0 + (w >> 5)) << 5) + (w & 31)];
    mb_l[t] = bitl[((size_t)(b * LQ_ + q0 + (t >> 4)) << 4) + (t & 15)];

    // Q fragments (16 rows), reused for both branches
    const bf16_t* Qb = Qh + (size_t)bh * LQ_ * DK_;
    bf16x8 qf[2];
#pragma unroll
    for (int ks = 0; ks < 2; ++ks)
        qf[ks] = *(const bf16x8*)&Qb[(size_t)(q0 + lr) * DK_ + ks * 32 + lk8];
    __syncthreads();

    // ---- branch c ----
    scores16<LK_>(Ssh, Kh + (size_t)bh * LK_ * DK_, qf, mb_c, wave, lane);
    __syncthreads();
    softmax16<LK_>(Ssh, Sc + (size_t)bh * LQ_ * LK_, invs_c, q0, wave, lane);
    __syncthreads();
    f32x4 acc_c = {};
    pv16<LK_>(Ssh, Vt + (size_t)bh * DK_ * LK_, acc_c, wave, lane);
    __syncthreads();
    // ---- branch l ----
    scores16<LKL_>(Ssh, Klh + (size_t)bh * LKL_ * DK_, qf, mb_l, wave, lane);
    __syncthreads();
    softmax16<LKL_>(Ssh, Sl + (size_t)bh * LQ_ * LKL_, invs_l, q0, wave, lane);
    __syncthreads();
    f32x4 acc_l = {};
    pv16<LKL_>(Ssh, Vlt + (size_t)bh * DK_ * LKL_, acc_l, wave, lane);

    // ---- epilogue: comb = 0.5*(Ec@V * inv_c + El@Vl * inv_l) ----
    const int d0 = wave * 16;
#pragma unroll
    for (int r = 0; r < 4; ++r) {
        const int lrow = (lane >> 4) * 4 + r;
        const int row = q0 + lrow;
        const float val = 0.5f * (acc_c[r] * invs_c[lrow] + acc_l[r] * invs_l[lrow]);
        comb[((size_t)b * LQ_ + row) * HDK_ + h * DK_ + d0 + (lane & 15)] = (bf16_t)val;
    }
}

// ---------------------------------------------------------------------------
// LayerNorm over last dim (1024).
// ---------------------------------------------------------------------------
__global__ __launch_bounds__(256) void ln_kernel(
    const float* __restrict__ Y, const float* __restrict__ g,
    const float* __restrict__ be, float* __restrict__ out)
{
    __shared__ float red1[4], red2[4];
    const int tid = threadIdx.x, wave = tid >> 6, lane = tid & 63;
    const float* p = Y + (size_t)blockIdx.x * DX_;
    const float4 x = *(const float4*)&p[tid * 4];
    float s  = x.x + x.y + x.z + x.w;
    float ss = x.x * x.x + x.y * x.y + x.z * x.z + x.w * x.w;
    s = waveSum(s); ss = waveSum(ss);
    if (lane == 0) { red1[wave] = s; red2[wave] = ss; }
    __syncthreads();
    s  = red1[0] + red1[1] + red1[2] + red1[3];
    ss = red2[0] + red2[1] + red2[2] + red2[3];
    const float mean = s * (1.f / DX_);
    const float var  = ss * (1.f / DX_) - mean * mean;
    const float rstd = rsqrtf(var + EPS_);
    const float4 gg = *(const float4*)&g[tid * 4];
    const float4 bb = *(const float4*)&be[tid * 4];
    float4 o;
    o.x = (x.x - mean) * rstd * gg.x + bb.x;
    o.y = (x.y - mean) * rstd * gg.y + bb.y;
    o.z = (x.z - mean) * rstd * gg.z + bb.z;
    o.w = (x.w - mean) * rstd * gg.w + bb.w;
    *(float4*)&out[(size_t)blockIdx.x * DX_ + tid * 4] = o;
}

// ---------------------------------------------------------------------------
extern "C" void kernel_launch(void* const* d_in, const int* in_sizes, int n_in,
                              void* d_out, int out_size, void* d_ws, size_t ws_size,
                              hipStream_t stream)
{
    const float* q    = (const float*)d_in[0];
    const float* k    = (const float*)d_in[1];
    const float* v    = (const float*)d_in[2];
    const float* kl   = (const float*)d_in[3];
    const float* vl   = (const float*)d_in[4];
    const void*  mask  = d_in[5];
    const void*  maskl = d_in[6];
    const float* wq_w  = (const float*)d_in[7];
    const float* wq_b  = (const float*)d_in[8];
    const float* wk_w  = (const float*)d_in[9];
    const float* wk_b  = (const float*)d_in[10];
    const float* wv_w  = (const float*)d_in[11];
    const float* wv_b  = (const float*)d_in[12];
    const float* wkl_w = (const float*)d_in[13];
    const float* wkl_b = (const float*)d_in[14];
    const float* wvl_w = (const float*)d_in[15];
    const float* wvl_b = (const float*)d_in[16];
    const float* wo_w  = (const float*)d_in[17];
    const float* wo_b  = (const float*)d_in[18];
    const float* ln_g  = (const float*)d_in[19];
    const float* ln_b  = (const float*)d_in[20];

    char* ws = (char*)d_ws;
    const size_t MiB = 1u << 20;
    bf16_t* qb   = (bf16_t*)(ws);                 //  0..8  (dead after q-proj)
    bf16_t* kb   = (bf16_t*)(ws +   8 * MiB);     //  8..16
    bf16_t* vb   = (bf16_t*)(ws +  16 * MiB);     // 16..24
    bf16_t* klb  = (bf16_t*)(ws +  24 * MiB);     // 24..28
    bf16_t* vlb  = (bf16_t*)(ws +  28 * MiB);     // 28..32
    bf16_t* qh   = (bf16_t*)(ws +  32 * MiB);     // 32..40
    bf16_t* kh   = (bf16_t*)(ws +  40 * MiB);     // 40..48
    bf16_t* klh  = (bf16_t*)(ws +  48 * MiB);     // 48..52
    bf16_t* vh   = (bf16_t*)(ws +  52 * MiB);     // 52..60
    bf16_t* vlh  = (bf16_t*)(ws +  60 * MiB);     // 60..64
    bf16_t* vt   = (bf16_t*)(ws +  64 * MiB);     // 64..72
    bf16_t* vlt  = (bf16_t*)(ws +  72 * MiB);     // 72..76
    bf16_t* wqT  = (bf16_t*)(ws +  76 * MiB);
    bf16_t* wkT  = (bf16_t*)(ws +  78 * MiB);
    bf16_t* wvT  = (bf16_t*)(ws +  80 * MiB);
    bf16_t* wklT = (bf16_t*)(ws +  82 * MiB);
    bf16_t* wvlT = (bf16_t*)(ws +  84 * MiB);
    bf16_t* woT  = (bf16_t*)(ws +  86 * MiB);
    unsigned* flag = (unsigned*)(ws + 88 * MiB);
    unsigned long long* bitc = (unsigned long long*)(ws + 89 * MiB);
    unsigned long long* bitl = (unsigned long long*)(ws + 89 * MiB + 512 * 1024);
    bf16_t* comb = (bf16_t*)(ws + 90 * MiB);      // 90..98
    float*  ypre = (float*) (ws);                 // 0..16 (qb/kb dead)

    float* y_out = (float*)d_out;
    float* Sc = y_out + (size_t)B_ * LQ_ * DX_;
    float* Sl = Sc + (size_t)B_ * H_ * LQ_ * LK_;

    detect_mask_kernel<<<dim3(1), dim3(256), 0, stream>>>((const unsigned*)mask, flag);
    bitpack_mask_kernel<<<dim3((B_*LQ_*(LK_+LKL_)) / 256), 256, 0, stream>>>(
        mask, maskl, flag, bitc, bitl);

    // Activations -> bf16
    cvt_bf16_kernel<<<2048, 256, 0, stream>>>(q,  qb,  524288);
    cvt_bf16_kernel<<<2048, 256, 0, stream>>>(k,  kb,  524288);
    cvt_bf16_kernel<<<2048, 256, 0, stream>>>(v,  vb,  524288);
    cvt_bf16_kernel<<<1024, 256, 0, stream>>>(kl, klb, 262144);
    cvt_bf16_kernel<<<1024, 256, 0, stream>>>(vl, vlb, 262144);

    // Weights -> bf16 transposed (NxK)
    wtrans_kernel<<<dim3(16, 16), 256, 0, stream>>>(wq_w,  wqT);
    wtrans_kernel<<<dim3(16, 16), 256, 0, stream>>>(wk_w,  wkT);
    wtrans_kernel<<<dim3(16, 16), 256, 0, stream>>>(wv_w,  wvT);
    wtrans_kernel<<<dim3(16, 16), 256, 0, stream>>>(wkl_w, wklT);
    wtrans_kernel<<<dim3(16, 16), 256, 0, stream>>>(wvl_w, wvlT);
    wtrans_kernel<<<dim3(16, 16), 256, 0, stream>>>(wo_w,  woT);

    // Projections
    gemm2_kernel<0><<<dim3(8, 32), 512, 0, stream>>>(qb,  wqT,  wq_b,  qh,  nullptr, 10);
    gemm2_kernel<0><<<dim3(8, 32), 512, 0, stream>>>(kb,  wkT,  wk_b,  kh,  nullptr, 10);
    gemm2_kernel<0><<<dim3(8, 16), 512, 0, stream>>>(klb, wklT, wkl_b, klh, nullptr,  9);
    gemm2_kernel<0><<<dim3(8, 32), 512, 0, stream>>>(vb,  wvT,  wv_b,  vh,  nullptr, 10);
    gemm2_kernel<0><<<dim3(8, 16), 512, 0, stream>>>(vlb, wvlT, wvl_b, vlh, nullptr,  9);

    // V head tensors -> transposed (B,H,DK,L)
    transpose_v_kernel<<<dim3(16, 64), 256, 0, stream>>>(vh,  vt,  LK_);
    transpose_v_kernel<<<dim3( 8, 64), 256, 0, stream>>>(vlh, vlt, LKL_);

    // Fused scores+softmax+PV
    fused_attn_kernel<<<dim3(4096), 256, 0, stream>>>(qh, kh, klh, vt, vlt,
                                                      (const unsigned*)bitc, (const unsigned*)bitl,
                                                      Sc, Sl, comb);

    // Output projection + bias + residual(q)
    gemm2_kernel<2><<<dim3(8, 32), 512, 0, stream>>>(comb, woT, wo_b, ypre, q, 0);

    // LayerNorm
    ln_kernel<<<4096, 256, 0, stream>>>(ypre, ln_g, ln_b, y_out);
}

// Round 6
// 404.737 us; speedup vs baseline: 1.5277x; 1.3873x over previous
//
#include <hip/hip_runtime.h>
#include <hip/hip_bf16.h>

#define B_   4
#define LQ_  1024
#define LK_  1024
#define LKL_ 512
#define DX_  1024
#define H_   16
#define DK_  64
#define HDK_ 1024
#define NEG_ -1e9f
#define EPS_ 1e-5f

typedef __bf16 bf16_t;
typedef __bf16 bf16x8 __attribute__((ext_vector_type(8)));
typedef __bf16 bf16x4 __attribute__((ext_vector_type(4)));
typedef float  f32x4  __attribute__((ext_vector_type(4)));

__device__ inline f32x4 mfma16(bf16x8 a, bf16x8 b, f32x4 c) {
    return __builtin_amdgcn_mfma_f32_16x16x32_bf16(a, b, c, 0, 0, 0);
}

__device__ __forceinline__ void gload16(const void* g, void* l) {
    __builtin_amdgcn_global_load_lds(
        (const __attribute__((address_space(1))) void*)g,
        (__attribute__((address_space(3))) void*)l, 16, 0, 0);
}

__device__ inline float waveMax(float v) {
#pragma unroll
    for (int o = 32; o > 0; o >>= 1) v = fmaxf(v, __shfl_xor(v, o, 64));
    return v;
}
__device__ inline float waveSum(float v) {
#pragma unroll
    for (int o = 32; o > 0; o >>= 1) v += __shfl_xor(v, o, 64);
    return v;
}

// XOR-swizzle: spread column-slice reads across banks (16B slots XOR row).
template<int STRIDE>
__device__ inline int sidx(int row, int col) {
    return (row * STRIDE + col) ^ ((row & 15) << 3);
}

// ---------------------------------------------------------------------------
// Detect mask materialization: int32 (0), uint8 (1), float32 (2).
// ---------------------------------------------------------------------------
__global__ void detect_mask_kernel(const unsigned* __restrict__ m, unsigned* __restrict__ flag)
{
    __shared__ unsigned w[256];
    w[threadIdx.x] = m[threadIdx.x];
    __syncthreads();
    if (threadIdx.x == 0) {
        bool all01 = true, allf = true;
        for (int i = 0; i < 256; ++i) {
            unsigned v = w[i];
            all01 = all01 && (v <= 1u);
            allf  = allf  && (v == 0u || v == 0x3F800000u);
        }
        *flag = all01 ? 0u : (allf ? 2u : 1u);
    }
}

// ---------------------------------------------------------------------------
// Bit-pack both masks (1 = masked).
// ---------------------------------------------------------------------------
__global__ __launch_bounds__(256) void bitpack_mask_kernel(
    const void* __restrict__ mc, const void* __restrict__ ml,
    const unsigned* __restrict__ flagp,
    unsigned long long* __restrict__ bc, unsigned long long* __restrict__ bl)
{
    const unsigned flag = *flagp;
    const size_t NC = (size_t)B_ * LQ_ * LK_;
    const int lane = threadIdx.x & 63;
    const size_t g = (size_t)blockIdx.x * 256 + threadIdx.x;
    const bool inC = g < NC;
    const size_t idx = inC ? g : g - NC;
    const void* src = inC ? mc : ml;
    bool m;
    if (flag == 0u)      m = ((const int*)src)[idx] != 0;
    else if (flag == 2u) m = ((const float*)src)[idx] != 0.0f;
    else                 m = ((const unsigned char*)src)[idx] != 0;
    const unsigned long long bal = __ballot(m);
    if (lane == 0) {
        unsigned long long* dst = inC ? bc : bl;
        dst[idx >> 6] = bal;
    }
}

// ---------------------------------------------------------------------------
// f32 -> bf16 convert (8 elems/thread).
// ---------------------------------------------------------------------------
__global__ __launch_bounds__(256) void cvt_bf16_kernel(
    const float* __restrict__ src, bf16_t* __restrict__ dst, int n8)
{
    const int i = blockIdx.x * 256 + threadIdx.x;
    if (i >= n8) return;
    const float4 a = ((const float4*)src)[i * 2];
    const float4 b = ((const float4*)src)[i * 2 + 1];
    bf16x8 o;
    o[0] = (bf16_t)a.x; o[1] = (bf16_t)a.y; o[2] = (bf16_t)a.z; o[3] = (bf16_t)a.w;
    o[4] = (bf16_t)b.x; o[5] = (bf16_t)b.y; o[6] = (bf16_t)b.z; o[7] = (bf16_t)b.w;
    ((bf16x8*)dst)[i] = o;
}

// ---------------------------------------------------------------------------
// Weight transpose + convert: W (1024x1024 f32, KxN) -> Wt (NxK bf16).
// ---------------------------------------------------------------------------
__global__ __launch_bounds__(256) void wtrans_kernel(
    const float* __restrict__ W, bf16_t* __restrict__ Wt)
{
    __shared__ float T[64][65];
    const int k0 = blockIdx.y * 64, n0 = blockIdx.x * 64;
    const int t = threadIdx.x;
    const int lr = t >> 2, c0 = (t & 3) * 16;
#pragma unroll
    for (int j = 0; j < 4; ++j) {
        const float4 v = *(const float4*)&W[(size_t)(k0 + lr) * DX_ + n0 + c0 + j * 4];
        T[lr][c0 + j * 4 + 0] = v.x; T[lr][c0 + j * 4 + 1] = v.y;
        T[lr][c0 + j * 4 + 2] = v.z; T[lr][c0 + j * 4 + 3] = v.w;
    }
    __syncthreads();
    const int dr = t >> 2;
    bf16x8 o0, o1;
#pragma unroll
    for (int j = 0; j < 8; ++j) {
        o0[j] = (bf16_t)T[c0 + j][dr];
        o1[j] = (bf16_t)T[c0 + 8 + j][dr];
    }
    *(bf16x8*)&Wt[(size_t)(n0 + dr) * DX_ + k0 + c0]     = o0;
    *(bf16x8*)&Wt[(size_t)(n0 + dr) * DX_ + k0 + c0 + 8] = o1;
}

// ---------------------------------------------------------------------------
// Transpose (bh, L, 64) -> (bh, 64, L) bf16 (coalesced both ways).
// ---------------------------------------------------------------------------
__global__ __launch_bounds__(256) void transpose_v_kernel(
    const bf16_t* __restrict__ V, bf16_t* __restrict__ Vt, int L)
{
    __shared__ bf16_t T[64][72];
    const int bh = blockIdx.y, l0 = blockIdx.x * 64;
    const bf16_t* Vb = V + (size_t)bh * L * 64;
    bf16_t* Vtb = Vt + (size_t)bh * 64 * L;
    const int t = threadIdx.x;
    {
        const int lr = t >> 2, dc = (t & 3) * 16;
        const bf16x8 a = *(const bf16x8*)&Vb[(size_t)(l0 + lr) * 64 + dc];
        const bf16x8 b = *(const bf16x8*)&Vb[(size_t)(l0 + lr) * 64 + dc + 8];
#pragma unroll
        for (int j = 0; j < 8; ++j) { T[lr][dc + j] = a[j]; T[lr][dc + 8 + j] = b[j]; }
    }
    __syncthreads();
    {
        const int dr = t >> 2, lc = (t & 3) * 16;
        bf16x8 o0, o1;
#pragma unroll
        for (int j = 0; j < 8; ++j) { o0[j] = T[lc + j][dr]; o1[j] = T[lc + 8 + j][dr]; }
        *(bf16x8*)&Vtb[(size_t)dr * L + l0 + lc]     = o0;
        *(bf16x8*)&Vtb[(size_t)dr * L + l0 + lc + 8] = o1;
    }
}

// ---------------------------------------------------------------------------
// m97-style GEMM: A(bf16 Mx1024) * Bt(bf16 1024x1024, = W^T) + bias.
// MODE 0: bf16 head (B,H,L,DK).  MODE 2: f32 + resid.
// ---------------------------------------------------------------------------
template<int MODE>
__global__ __launch_bounds__(512, 2) void gemm2_kernel(
    const bf16_t* __restrict__ A, const bf16_t* __restrict__ Bt,
    const float* __restrict__ bias,
    void* __restrict__ out, const float* __restrict__ resid, int lshift)
{
    __shared__ bf16_t As[128 * 64];
    __shared__ bf16_t Bs[128 * 64];
    char* const AsB = (char*)As;
    char* const BsB = (char*)Bs;
    const int tid = threadIdx.x, wave = tid >> 6, lane = tid & 63;
    const int m0 = blockIdx.y * 128, n0 = blockIdx.x * 128;
    const int wr4 = (wave >> 1) * 32, wc2 = (wave & 1) * 64;

    f32x4 acc[2][4] = {};

    const int srow = wave * 8 + (lane >> 3);
    const int sslot = lane & 7;

    for (int k0 = 0; k0 < 1024; k0 += 64) {
        __syncthreads();
#pragma unroll
        for (int j = 0; j < 2; ++j) {
            const int row = srow + j * 64;
            const int gs = sslot ^ (row & 7);
            gload16(&A[(size_t)(m0 + row) * 1024 + k0 + gs * 8],
                    AsB + j * 8192 + wave * 1024);
            gload16(&Bt[(size_t)(n0 + row) * 1024 + k0 + gs * 8],
                    BsB + j * 8192 + wave * 1024);
        }
        __syncthreads();
#pragma unroll
        for (int kk = 0; kk < 2; ++kk) {
            bf16x8 av[2], bv[4];
#pragma unroll
            for (int i = 0; i < 2; ++i) {
                const int r = wr4 + i * 16 + (lane & 15);
                av[i] = *(const bf16x8*)(AsB + r * 128 + (((kk * 4 + (lane >> 4)) ^ (r & 7)) * 16));
            }
#pragma unroll
            for (int n = 0; n < 4; ++n) {
                const int r = wc2 + n * 16 + (lane & 15);
                bv[n] = *(const bf16x8*)(BsB + r * 128 + (((kk * 4 + (lane >> 4)) ^ (r & 7)) * 16));
            }
#pragma unroll
            for (int i = 0; i < 2; ++i)
#pragma unroll
                for (int n = 0; n < 4; ++n)
                    acc[i][n] = mfma16(av[i], bv[n], acc[i][n]);
        }
    }

#pragma unroll
    for (int i = 0; i < 2; ++i) {
#pragma unroll
        for (int n = 0; n < 4; ++n) {
            const int col = n0 + wc2 + n * 16 + (lane & 15);
            const float bs = bias[col];
            const int row0 = m0 + wr4 + i * 16 + (lane >> 4) * 4;
            if (MODE == 0) {
                const int b = row0 >> lshift, l = row0 & ((1 << lshift) - 1);
                const int h = col >> 6, d = col & 63;
#pragma unroll
                for (int r = 0; r < 4; ++r)
                    ((bf16_t*)out)[(((size_t)(b * H_ + h) << lshift) + l + r) * DK_ + d] =
                        (bf16_t)(acc[i][n][r] + bs);
            } else {
#pragma unroll
                for (int r = 0; r < 4; ++r) {
                    const size_t idx = (size_t)(row0 + r) * DX_ + col;
                    ((float*)out)[idx] = acc[i][n][r] + bs + resid[idx];
                }
            }
        }
    }
}

// ---------------------------------------------------------------------------
// One attention branch per kernel (R3 structure): 16 q-rows/block, 4 waves,
// scores(masked)->LDS, register softmax (normalized probs -> global + LDS),
// PV from LDS. COMBINE: comb += 0.5*O (read-modify-write, kernels serialize).
// ---------------------------------------------------------------------------
template<int LKX, bool COMBINE>
__device__ __forceinline__ void fused_branch_body(
    const bf16_t* __restrict__ Qh, const bf16_t* __restrict__ Kh,
    const bf16_t* __restrict__ Vt, const unsigned* __restrict__ bits,
    float* __restrict__ S, bf16_t* __restrict__ comb, bf16_t* __restrict__ Ssh)
{
    const int sid = (blockIdx.x & 7) * 512 + (blockIdx.x >> 3);
    const int bh = sid >> 6, qt = sid & 63;
    const int b = bh >> 4, h = bh & 15;
    const int q0 = qt * 16;
    const int wave = threadIdx.x >> 6, lane = threadIdx.x & 63;
    const int lr = lane & 15, lk8 = (lane >> 4) * 8;
    constexpr int WORDS = LKX / 32;

    const bf16_t* Qb  = Qh + (size_t)bh * LQ_ * DK_;
    const bf16_t* Kb  = Kh + (size_t)bh * LKX * DK_;
    const bf16_t* Vtb = Vt + (size_t)bh * DK_ * LKX;
    float* Sout = S + (size_t)bh * LQ_ * LKX;

    bf16x8 qf[2];
#pragma unroll
    for (int ks = 0; ks < 2; ++ks)
        qf[ks] = *(const bf16x8*)&Qb[(size_t)(q0 + lr) * DK_ + ks * 32 + lk8];

    // ---- scores (masked at write-back) ----
    constexpr int KTS = LKX / 64;
#pragma unroll
    for (int kt = 0; kt < KTS; ++kt) {
        const int kbase = wave * (LKX / 4) + kt * 16;
        f32x4 acc = {};
#pragma unroll
        for (int ks = 0; ks < 2; ++ks) {
            const bf16x8 bb = *(const bf16x8*)&Kb[(size_t)(kbase + lr) * DK_ + ks * 32 + lk8];
            acc = mfma16(qf[ks], bb, acc);
        }
        const int wi = kbase >> 5;
        const int sh = (kbase & 16) + (lane & 15);
#pragma unroll
        for (int r = 0; r < 4; ++r) {
            const int row = (lane >> 4) * 4 + r;
            const unsigned word = bits[(size_t)(b * LQ_ + q0 + row) * WORDS + wi];
            const bool msk = (word >> sh) & 1u;
            Ssh[sidx<LKX>(row, kbase + (lane & 15))] = (bf16_t)(msk ? NEG_ : acc[r] * 0.125f);
        }
    }
    __syncthreads();

    // ---- softmax: 4 rows/wave, register row buffer, normalized write ----
    constexpr int NP = LKX / 256;
#pragma unroll 1
    for (int i = 0; i < 4; ++i) {
        const int row = wave * 4 + i;
        const int rowg = q0 + row;
        float p[NP * 4];
        float m = -INFINITY;
#pragma unroll
        for (int ps = 0; ps < NP; ++ps) {
            const bf16x4 sv = *(const bf16x4*)&Ssh[sidx<LKX>(row, ps * 256 + lane * 4)];
#pragma unroll
            for (int j = 0; j < 4; ++j) {
                p[ps * 4 + j] = (float)sv[j];
                m = fmaxf(m, p[ps * 4 + j]);
            }
        }
        m = waveMax(m);
        float s = 0.f;
#pragma unroll
        for (int j = 0; j < NP * 4; ++j) { p[j] = __expf(p[j] - m); s += p[j]; }
        s = waveSum(s);
        const float inv = 1.f / s;
#pragma unroll
        for (int ps = 0; ps < NP; ++ps) {
            const int col = ps * 256 + lane * 4;
            f32x4 o; bf16x4 pb;
#pragma unroll
            for (int j = 0; j < 4; ++j) {
                const float v = p[ps * 4 + j] * inv;
                o[j] = v; pb[j] = (bf16_t)v;
            }
            __builtin_nontemporal_store(o, (f32x4*)&Sout[(size_t)rowg * LKX + col]);
            *(bf16x4*)&Ssh[sidx<LKX>(row, col)] = pb;
        }
    }
    __syncthreads();

    // ---- PV ----
    f32x4 acc_o = {};
    const int d0 = wave * 16;
#pragma unroll
    for (int ks = 0; ks < LKX / 32; ++ks) {
        const bf16x8 bb = *(const bf16x8*)&Vtb[(size_t)(d0 + lr) * LKX + ks * 32 + lk8];
        const bf16x8 a  = *(const bf16x8*)&Ssh[sidx<LKX>(lr, ks * 32 + lk8)];
        acc_o = mfma16(a, bb, acc_o);
    }

    // ---- epilogue ----
#pragma unroll
    for (int r = 0; r < 4; ++r) {
        const int row = q0 + (lane >> 4) * 4 + r;
        const size_t idx = ((size_t)b * LQ_ + row) * HDK_ + h * DK_ + d0 + (lane & 15);
        const float half = 0.5f * acc_o[r];
        if (COMBINE) comb[idx] = (bf16_t)((float)comb[idx] + half);
        else         comb[idx] = (bf16_t)half;
    }
}

__global__ __launch_bounds__(256, 3) void fused_c_kernel(
    const bf16_t* __restrict__ Qh, const bf16_t* __restrict__ Kh,
    const bf16_t* __restrict__ Vt, const unsigned* __restrict__ bits,
    float* __restrict__ S, bf16_t* __restrict__ comb)
{
    __shared__ bf16_t Ssh[16 * LK_];    // exactly 32 KB
    fused_branch_body<LK_, false>(Qh, Kh, Vt, bits, S, comb, Ssh);
}

__global__ __launch_bounds__(256, 3) void fused_l_kernel(
    const bf16_t* __restrict__ Qh, const bf16_t* __restrict__ Kh,
    const bf16_t* __restrict__ Vt, const unsigned* __restrict__ bits,
    float* __restrict__ S, bf16_t* __restrict__ comb)
{
    __shared__ bf16_t Ssh[16 * LKL_];   // exactly 16 KB
    fused_branch_body<LKL_, true>(Qh, Kh, Vt, bits, S, comb, Ssh);
}

// ---------------------------------------------------------------------------
// LayerNorm over last dim (1024).
// ---------------------------------------------------------------------------
__global__ __launch_bounds__(256) void ln_kernel(
    const float* __restrict__ Y, const float* __restrict__ g,
    const float* __restrict__ be, float* __restrict__ out)
{
    __shared__ float red1[4], red2[4];
    const int tid = threadIdx.x, wave = tid >> 6, lane = tid & 63;
    const float* p = Y + (size_t)blockIdx.x * DX_;
    const float4 x = *(const float4*)&p[tid * 4];
    float s  = x.x + x.y + x.z + x.w;
    float ss = x.x * x.x + x.y * x.y + x.z * x.z + x.w * x.w;
    s = waveSum(s); ss = waveSum(ss);
    if (lane == 0) { red1[wave] = s; red2[wave] = ss; }
    __syncthreads();
    s  = red1[0] + red1[1] + red1[2] + red1[3];
    ss = red2[0] + red2[1] + red2[2] + red2[3];
    const float mean = s * (1.f / DX_);
    const float var  = ss * (1.f / DX_) - mean * mean;
    const float rstd = rsqrtf(var + EPS_);
    const float4 gg = *(const float4*)&g[tid * 4];
    const float4 bb = *(const float4*)&be[tid * 4];
    float4 o;
    o.x = (x.x - mean) * rstd * gg.x + bb.x;
    o.y = (x.y - mean) * rstd * gg.y + bb.y;
    o.z = (x.z - mean) * rstd * gg.z + bb.z;
    o.w = (x.w - mean) * rstd * gg.w + bb.w;
    *(float4*)&out[(size_t)blockIdx.x * DX_ + tid * 4] = o;
}

// ---------------------------------------------------------------------------
extern "C" void kernel_launch(void* const* d_in, const int* in_sizes, int n_in,
                              void* d_out, int out_size, void* d_ws, size_t ws_size,
                              hipStream_t stream)
{
    const float* q    = (const float*)d_in[0];
    const float* k    = (const float*)d_in[1];
    const float* v    = (const float*)d_in[2];
    const float* kl   = (const float*)d_in[3];
    const float* vl   = (const float*)d_in[4];
    const void*  mask  = d_in[5];
    const void*  maskl = d_in[6];
    const float* wq_w  = (const float*)d_in[7];
    const float* wq_b  = (const float*)d_in[8];
    const float* wk_w  = (const float*)d_in[9];
    const float* wk_b  = (const float*)d_in[10];
    const float* wv_w  = (const float*)d_in[11];
    const float* wv_b  = (const float*)d_in[12];
    const float* wkl_w = (const float*)d_in[13];
    const float* wkl_b = (const float*)d_in[14];
    const float* wvl_w = (const float*)d_in[15];
    const float* wvl_b = (const float*)d_in[16];
    const float* wo_w  = (const float*)d_in[17];
    const float* wo_b  = (const float*)d_in[18];
    const float* ln_g  = (const float*)d_in[19];
    const float* ln_b  = (const float*)d_in[20];

    char* ws = (char*)d_ws;
    const size_t MiB = 1u << 20;
    bf16_t* qb   = (bf16_t*)(ws);                 //  0..8  (dead after q-proj)
    bf16_t* kb   = (bf16_t*)(ws +   8 * MiB);     //  8..16
    bf16_t* vb   = (bf16_t*)(ws +  16 * MiB);     // 16..24
    bf16_t* klb  = (bf16_t*)(ws +  24 * MiB);     // 24..28
    bf16_t* vlb  = (bf16_t*)(ws +  28 * MiB);     // 28..32
    bf16_t* qh   = (bf16_t*)(ws +  32 * MiB);     // 32..40
    bf16_t* kh   = (bf16_t*)(ws +  40 * MiB);     // 40..48
    bf16_t* klh  = (bf16_t*)(ws +  48 * MiB);     // 48..52
    bf16_t* vh   = (bf16_t*)(ws +  52 * MiB);     // 52..60
    bf16_t* vlh  = (bf16_t*)(ws +  60 * MiB);     // 60..64
    bf16_t* vt   = (bf16_t*)(ws +  64 * MiB);     // 64..72
    bf16_t* vlt  = (bf16_t*)(ws +  72 * MiB);     // 72..76
    bf16_t* wqT  = (bf16_t*)(ws +  76 * MiB);
    bf16_t* wkT  = (bf16_t*)(ws +  78 * MiB);
    bf16_t* wvT  = (bf16_t*)(ws +  80 * MiB);
    bf16_t* wklT = (bf16_t*)(ws +  82 * MiB);
    bf16_t* wvlT = (bf16_t*)(ws +  84 * MiB);
    bf16_t* woT  = (bf16_t*)(ws +  86 * MiB);
    unsigned* flag = (unsigned*)(ws + 88 * MiB);
    unsigned long long* bitc = (unsigned long long*)(ws + 89 * MiB);
    unsigned long long* bitl = (unsigned long long*)(ws + 89 * MiB + 512 * 1024);
    bf16_t* comb = (bf16_t*)(ws + 90 * MiB);      // 90..98
    float*  ypre = (float*) (ws);                 // 0..16 (qb/kb dead)

    float* y_out = (float*)d_out;
    float* Sc = y_out + (size_t)B_ * LQ_ * DX_;
    float* Sl = Sc + (size_t)B_ * H_ * LQ_ * LK_;

    detect_mask_kernel<<<dim3(1), dim3(256), 0, stream>>>((const unsigned*)mask, flag);
    bitpack_mask_kernel<<<dim3((B_*LQ_*(LK_+LKL_)) / 256), 256, 0, stream>>>(
        mask, maskl, flag, bitc, bitl);

    // Activations -> bf16
    cvt_bf16_kernel<<<2048, 256, 0, stream>>>(q,  qb,  524288);
    cvt_bf16_kernel<<<2048, 256, 0, stream>>>(k,  kb,  524288);
    cvt_bf16_kernel<<<2048, 256, 0, stream>>>(v,  vb,  524288);
    cvt_bf16_kernel<<<1024, 256, 0, stream>>>(kl, klb, 262144);
    cvt_bf16_kernel<<<1024, 256, 0, stream>>>(vl, vlb, 262144);

    // Weights -> bf16 transposed (NxK)
    wtrans_kernel<<<dim3(16, 16), 256, 0, stream>>>(wq_w,  wqT);
    wtrans_kernel<<<dim3(16, 16), 256, 0, stream>>>(wk_w,  wkT);
    wtrans_kernel<<<dim3(16, 16), 256, 0, stream>>>(wv_w,  wvT);
    wtrans_kernel<<<dim3(16, 16), 256, 0, stream>>>(wkl_w, wklT);
    wtrans_kernel<<<dim3(16, 16), 256, 0, stream>>>(wvl_w, wvlT);
    wtrans_kernel<<<dim3(16, 16), 256, 0, stream>>>(wo_w,  woT);

    // Projections
    gemm2_kernel<0><<<dim3(8, 32), 512, 0, stream>>>(qb,  wqT,  wq_b,  qh,  nullptr, 10);
    gemm2_kernel<0><<<dim3(8, 32), 512, 0, stream>>>(kb,  wkT,  wk_b,  kh,  nullptr, 10);
    gemm2_kernel<0><<<dim3(8, 16), 512, 0, stream>>>(klb, wklT, wkl_b, klh, nullptr,  9);
    gemm2_kernel<0><<<dim3(8, 32), 512, 0, stream>>>(vb,  wvT,  wv_b,  vh,  nullptr, 10);
    gemm2_kernel<0><<<dim3(8, 16), 512, 0, stream>>>(vlb, wvlT, wvl_b, vlh, nullptr,  9);

    // V head tensors -> transposed (B,H,DK,L)
    transpose_v_kernel<<<dim3(16, 64), 256, 0, stream>>>(vh,  vt,  LK_);
    transpose_v_kernel<<<dim3( 8, 64), 256, 0, stream>>>(vlh, vlt, LKL_);

    // Attention branch c (writes Sc + comb = 0.5*Oc), then branch l
    // (writes Sl, comb += 0.5*Ol). Kernels serialize on the stream.
    fused_c_kernel<<<dim3(4096), 256, 0, stream>>>(qh, kh,  vt,  (const unsigned*)bitc, Sc, comb);
    fused_l_kernel<<<dim3(4096), 256, 0, stream>>>(qh, klh, vlt, (const unsigned*)bitl, Sl, comb);

    // Output projection + bias + residual(q)
    gemm2_kernel<2><<<dim3(8, 32), 512, 0, stream>>>(comb, woT, wo_b, ypre, q, 0);

    // LayerNorm
    ln_kernel<<<4096, 256, 0, stream>>>(ypre, ln_g, ln_b, y_out);
}